// Round 9
// baseline (1035.874 us; speedup 1.0000x reference)
//
#include <hip/hip_runtime.h>
#include <math.h>

#define N_NODES 100000
#define N_EDGES 1600000
#define IN_DIM 500
#define HID 64
#define NCLS 16
#define KP 512     // padded K for layer-1 GEMM
#define NSTEPS 16  // KP/32
#define NBUK 782   // buckets of 128 dsts: bucket = dst >> 7 (max 99999>>7 = 781)
#define EPB 4096   // edges per bucket-phase block

typedef __attribute__((ext_vector_type(8))) short short8;
typedef __attribute__((ext_vector_type(4))) float f32x4;

__device__ __forceinline__ unsigned short f2bf(float f) {
    unsigned u = __builtin_bit_cast(unsigned, f);
    return (unsigned short)((u + 0x7FFFu + ((u >> 16) & 1u)) >> 16);
}
__device__ __forceinline__ float bf2f(unsigned short s) {
    unsigned u = ((unsigned)s) << 16;
    return __builtin_bit_cast(float, u);
}
__device__ __forceinline__ unsigned pack2(unsigned short a, unsigned short b) {
    return (unsigned)a | ((unsigned)b << 16);
}
// async global->LDS, 16B per lane; LDS dest is wave-uniform base + lane*16
__device__ __forceinline__ void gload16(const void* g, void* l) {
    __builtin_amdgcn_global_load_lds(
        (const __attribute__((address_space(1))) unsigned*)g,
        (__attribute__((address_space(3))) unsigned*)l, 16, 0, 0);
}

// ---------------------------------------------------------------------------
// K0: build Bt[192][512] bf16 = transpose of {w1[0], w1[1], root1}, zero-pad K.
// ---------------------------------------------------------------------------
__global__ __launch_bounds__(256) void k0_bt(
    const float* __restrict__ w1, const float* __restrict__ root1,
    unsigned short* __restrict__ Bt)
{
    const int b = blockIdx.x;  // 0..191
    const float* src;
    int c;
    if (b < 64)        { src = w1;                c = b; }
    else if (b < 128)  { src = w1 + IN_DIM * HID; c = b - 64; }
    else               { src = root1;             c = b - 128; }
    for (int k = threadIdx.x; k < KP; k += 256) {
        float v = (k < IN_DIM) ? src[k * HID + c] : 0.f;
        Bt[b * KP + k] = f2bf(v);
    }
}

// ---------------------------------------------------------------------------
// Bucket build: bzero -> bhist (LDS hist) -> bscan (1 block) -> bucket scatter.
// Record: x = src, y = (dstlow7<<24) | v_fixed24. No per-dst sort needed.
// ---------------------------------------------------------------------------
__global__ __launch_bounds__(1024) void csr_bzero(int* __restrict__ bkcnt)
{
    if (threadIdx.x < NBUK) bkcnt[threadIdx.x] = 0;
}

__global__ __launch_bounds__(256) void csr_bhist(
    const int* __restrict__ ei, int* __restrict__ bkcnt)
{
    __shared__ int h[NBUK];
    const int tid = threadIdx.x;
    for (int i = tid; i < NBUK; i += 256) h[i] = 0;
    __syncthreads();
    const int start = blockIdx.x * EPB;
    const int eend = min(start + EPB, N_EDGES);
#pragma unroll
    for (int j = 0; j < EPB / 256; ++j) {
        const int e = start + j * 256 + tid;
        if (e < eend) atomicAdd(&h[ei[N_EDGES + e] >> 7], 1);
    }
    __syncthreads();
    for (int i = tid; i < NBUK; i += 256)
        if (h[i]) atomicAdd(&bkcnt[i], h[i]);
}

__global__ __launch_bounds__(1024) void csr_bscan(
    const int* __restrict__ bkcnt, int* __restrict__ bkoff, int* __restrict__ bkcur)
{
    __shared__ int s[1024];
    const int t = threadIdx.x;
    const int val = (t < NBUK) ? bkcnt[t] : 0;
    s[t] = val;
    for (int d = 1; d < 1024; d <<= 1) {
        __syncthreads();
        int add = (t >= d) ? s[t - d] : 0;
        __syncthreads();
        s[t] += add;
    }
    __syncthreads();
    if (t < NBUK) {
        const int o = s[t] - val;
        bkoff[t] = o;
        bkcur[t] = o;
    }
    if (t == NBUK - 1) bkoff[NBUK] = s[t];  // == N_EDGES
}

__global__ __launch_bounds__(256) void csr_bucket(
    const int* __restrict__ ei, const float* __restrict__ ea,
    int* __restrict__ bkcur, uint2* __restrict__ epk)
{
    __shared__ int hcnt[NBUK];
    __shared__ int hbase[NBUK];

    const int tid = threadIdx.x;
    const int start = blockIdx.x * EPB;
    const int eend = min(start + EPB, N_EDGES);

    for (int i = tid; i < NBUK; i += 256) hcnt[i] = 0;
    __syncthreads();

#pragma unroll
    for (int j = 0; j < EPB / 256; ++j) {
        const int e = start + j * 256 + tid;
        if (e < eend) atomicAdd(&hcnt[ei[N_EDGES + e] >> 7], 1);
    }
    __syncthreads();

    for (int b = tid; b < NBUK; b += 256) {
        const int c = hcnt[b];
        hbase[b] = c ? atomicAdd(&bkcur[b], c) : 0;
    }
    __syncthreads();
    for (int i = tid; i < NBUK; i += 256) hcnt[i] = 0;
    __syncthreads();

#pragma unroll
    for (int j = 0; j < EPB / 256; ++j) {
        const int e = start + j * 256 + tid;
        if (e < eend) {
            const int src = ei[e];
            const int dst = ei[N_EDGES + e];
            const float v = fminf(fmaxf(ea[e], 0.f), 1.f - 1e-6f);
            const unsigned vq = (unsigned)(v * 16777216.0f);  // 24-bit fixed
            const int bk = dst >> 7;
            const int r = atomicAdd(&hcnt[bk], 1);
            epk[hbase[bk] + r] =
                make_uint2((unsigned)src, ((unsigned)(dst & 127) << 24) | vq);
        }
    }
}

// ---------------------------------------------------------------------------
// K1: bf16 MFMA GEMM. global_load_lds staging (A fp32, B bf16), FOUR LDS
// buffers, depth-2 prefetch, counted vmcnt + raw s_barrier (T3/T4 minimum).
// Tile: 64 rows x 192 cols, BK=32. 4 waves in 2x2.
// ---------------------------------------------------------------------------
union K1Smem {
    struct { float A[4][64 * 32]; unsigned short B[4][192 * 32]; } s;  // 80KB
    unsigned short O[64 * 264];  // epilogue staging (33.8 KB)
};

__global__ __launch_bounds__(256) void k1_mfma(
    const float* __restrict__ x, const unsigned short* __restrict__ Bt,
    unsigned short* __restrict__ xw01, float* __restrict__ aggH)
{
    __shared__ K1Smem sm;

    const int tid = threadIdx.x;
    const int row0 = blockIdx.x * 64;
    const int w = tid >> 6;
    const int l = tid & 63;
    const int l16 = l & 15;
    const int koct = l >> 4;
    const int wr = w >> 1;
    const int wc = w & 1;

    f32x4 acc[2][6];
#pragma unroll
    for (int i = 0; i < 2; ++i)
#pragma unroll
        for (int j = 0; j < 6; ++j) acc[i][j] = (f32x4){0.f, 0.f, 0.f, 0.f};

    const int aJg4 = (((l & 7) ^ (l >> 3)) * 4);
    const float* aBase[2];
    int aLdsOff[2];
#pragma unroll
    for (int i = 0; i < 2; ++i) {
        const int rowl = (2 * w + i) * 8 + (l >> 3);
        int grow = row0 + rowl;
        if (grow > N_NODES - 1) grow = N_NODES - 1;
        aBase[i] = x + (size_t)grow * IN_DIM;
        aLdsOff[i] = (2 * w + i) * 256;  // floats
    }
    const int bJg8 = (((l & 3) ^ ((l >> 3) & 3)) * 8);
    const unsigned short* bBase[3];
    int bLdsOff[3];
#pragma unroll
    for (int i = 0; i < 3; ++i) {
        const int coll = (3 * w + i) * 16 + (l >> 2);
        bBase[i] = Bt + (size_t)coll * KP + bJg8;
        bLdsOff[i] = (3 * w + i) * 512;  // ushorts
    }

    const int ja0 = ((2 * koct) ^ (l16 & 7)) * 4;
    const int ja1 = ((2 * koct + 1) ^ (l16 & 7)) * 4;
    const int jb = (koct ^ ((l16 >> 1) & 3)) * 8;

    auto ISSUE = [&](int s) {
        const int k0 = s * 32;
        const int buf = s & 3;
#pragma unroll
        for (int i = 0; i < 2; ++i) {
            int gk = k0 + aJg4; if (gk > IN_DIM - 4) gk = IN_DIM - 4;
            gload16(aBase[i] + gk, &sm.s.A[buf][aLdsOff[i]]);
        }
#pragma unroll
        for (int i = 0; i < 3; ++i)
            gload16(bBase[i] + k0, &sm.s.B[buf][bLdsOff[i]]);
    };

    ISSUE(0);
    ISSUE(1);

#pragma unroll
    for (int s = 0; s < NSTEPS; ++s) {
        if (s + 2 < NSTEPS) ISSUE(s + 2);
        if (s < NSTEPS - 2)       asm volatile("s_waitcnt vmcnt(10)" ::: "memory");
        else if (s == NSTEPS - 2) asm volatile("s_waitcnt vmcnt(5)" ::: "memory");
        else                      asm volatile("s_waitcnt vmcnt(0)" ::: "memory");
        __builtin_amdgcn_s_barrier();
        asm volatile("" ::: "memory");

        const int buf = s & 3;
        const float* LA = sm.s.A[buf];
        const unsigned short* LB = sm.s.B[buf];
        short8 af[2];
#pragma unroll
        for (int rb = 0; rb < 2; ++rb) {
            const int r = wr * 32 + rb * 16 + l16;
            f32x4 f0 = *(const f32x4*)&LA[r * 32 + ja0];
            f32x4 f1 = *(const f32x4*)&LA[r * 32 + ja1];
            short8 a;
            a[0] = (short)f2bf(f0[0]); a[1] = (short)f2bf(f0[1]);
            a[2] = (short)f2bf(f0[2]); a[3] = (short)f2bf(f0[3]);
            a[4] = (short)f2bf(f1[0]); a[5] = (short)f2bf(f1[1]);
            a[6] = (short)f2bf(f1[2]); a[7] = (short)f2bf(f1[3]);
            af[rb] = a;
        }
#pragma unroll
        for (int cf = 0; cf < 6; ++cf) {
            const int c = wc * 96 + cf * 16 + l16;
            short8 bfg = *(const short8*)&LB[c * 32 + jb];
            acc[0][cf] = __builtin_amdgcn_mfma_f32_16x16x32_bf16(af[0], bfg, acc[0][cf], 0, 0, 0);
            acc[1][cf] = __builtin_amdgcn_mfma_f32_16x16x32_bf16(af[1], bfg, acc[1][cf], 0, 0, 0);
        }
    }
    __syncthreads();

#pragma unroll
    for (int rb = 0; rb < 2; ++rb)
#pragma unroll
        for (int cf = 0; cf < 6; ++cf) {
            const int cg = wc * 96 + cf * 16 + l16;
            if (96 * wc + cf * 16 < 128) {
#pragma unroll
                for (int reg = 0; reg < 4; ++reg) {
                    const int rloc = wr * 32 + rb * 16 + koct * 4 + reg;
                    const int idx = (cg < 64) ? (2 * cg) : (2 * cg - 127);
                    sm.O[rloc * 264 + idx] = f2bf(acc[rb][cf][reg]);
                }
            } else {
#pragma unroll
                for (int reg = 0; reg < 4; ++reg) {
                    const int r = row0 + wr * 32 + rb * 16 + koct * 4 + reg;
                    if (r < N_NODES) aggH[(size_t)r * HID + (cg - 128)] = acc[rb][cf][reg];
                }
            }
        }
    __syncthreads();
    {
        const int row = tid >> 2, q = tid & 3;
        const int rg = row0 + row;
        if (rg < N_NODES) {
#pragma unroll
            for (int j = 0; j < 4; ++j) {
                uint4 v = *(const uint4*)&sm.O[row * 264 + q * 32 + j * 8];
                *(uint4*)&xw01[(size_t)rg * 128 + q * 32 + j * 8] = v;
            }
        }
    }
}

// ---------------------------------------------------------------------------
// AGG1B: one block per 128-dst bucket. LDS fp32 accumulator (32 KB);
// records need not be dst-sorted. Epilogue: aggH += acc (root already there).
// ---------------------------------------------------------------------------
__global__ __launch_bounds__(512) void agg1b(
    const int* __restrict__ bkoff, const uint2* __restrict__ epk,
    const unsigned* __restrict__ xw01_u, float* __restrict__ aggH)
{
    __shared__ float acc[128 * 64];  // 32 KB

    const int b = blockIdx.x;
    const int tid = threadIdx.x;
    const int start = bkoff[b];
    const int cnt = bkoff[b + 1] - start;

    for (int i = tid; i < 128 * 64; i += 512) acc[i] = 0.f;
    __syncthreads();

    const int wv = tid >> 6;  // 8 waves
    const int d = tid & 63;
    for (int base = wv * 4; base < cnt; base += 32) {
        uint2 u[4];
        bool ok[4];
#pragma unroll
        for (int j = 0; j < 4; ++j) {
            ok[j] = (base + j) < cnt;
            u[j] = epk[start + (ok[j] ? base + j : base)];
        }
        unsigned g[4];
#pragma unroll
        for (int j = 0; j < 4; ++j)
            g[j] = xw01_u[(size_t)u[j].x * 64 + d];
#pragma unroll
        for (int j = 0; j < 4; ++j) {
            if (ok[j]) {
                const int dl = u[j].y >> 24;
                const float v = (float)(u[j].y & 0xFFFFFFu) * 5.9604644775390625e-8f;
                const float m = (1.f - v) * bf2f((unsigned short)(g[j] & 0xFFFF)) +
                                v * bf2f((unsigned short)(g[j] >> 16));
                atomicAdd(&acc[dl * 64 + d], m);
            }
        }
    }
    __syncthreads();

    for (int i = tid; i < 128 * 64; i += 512) {
        const int n = (b << 7) + (i >> 6);
        if (n < N_NODES) aggH[(size_t)n * HID + (i & 63)] += acc[i];
    }
}

// ---------------------------------------------------------------------------
// K3: h = relu(aggH + b1); hw01 = packed bf16 {h@w2[0], h@w2[1]}; agg2 = h@root2.
// ---------------------------------------------------------------------------
__global__ __launch_bounds__(256) void k3_relu_gemm(
    const float* __restrict__ aggH, const float* __restrict__ b1,
    const float* __restrict__ w2, const float* __restrict__ root2,
    unsigned* __restrict__ hw01_u, float* __restrict__ agg2)
{
    __shared__ float Ws[3 * HID * NCLS];
    __shared__ float Hs[16][HID];

    const int tid = threadIdx.x;
    for (int i = tid; i < 2 * HID * NCLS; i += 256) Ws[i] = w2[i];
    for (int i = tid; i < HID * NCLS; i += 256) Ws[2 * HID * NCLS + i] = root2[i];

    const int n0 = blockIdx.x * 16;
    for (int i = tid; i < 16 * HID; i += 256) {
        const int nl = i >> 6, k = i & 63;
        const float h = aggH[(size_t)(n0 + nl) * HID + k] + b1[k];
        Hs[nl][k] = fmaxf(h, 0.f);
    }
    __syncthreads();

    const int nl = tid >> 4;
    const int c = tid & 15;
    float a0 = 0.f, a1 = 0.f, a2 = 0.f;
#pragma unroll
    for (int k = 0; k < HID; ++k) {
        const float h = Hs[nl][k];
        a0 += h * Ws[0 * HID * NCLS + k * NCLS + c];
        a1 += h * Ws[1 * HID * NCLS + k * NCLS + c];
        a2 += h * Ws[2 * HID * NCLS + k * NCLS + c];
    }
    const size_t o = (size_t)(n0 + nl) * NCLS + c;
    hw01_u[o] = pack2(f2bf(a0), f2bf(a1));
    agg2[o] = a2;
}

// ---------------------------------------------------------------------------
// AGG2B + log_softmax: one block per 128-dst bucket, LDS acc[128][16] (8 KB),
// 16 lanes per edge; softmax fused in epilogue.
// ---------------------------------------------------------------------------
__global__ __launch_bounds__(512) void agg2b_sm(
    const int* __restrict__ bkoff, const uint2* __restrict__ epk,
    const unsigned* __restrict__ hw01_u, const float* __restrict__ agg2,
    const float* __restrict__ b2, float* __restrict__ out)
{
    __shared__ float acc[128 * 16];  // 8 KB

    const int b = blockIdx.x;
    const int tid = threadIdx.x;
    const int start = bkoff[b];
    const int cnt = bkoff[b + 1] - start;

    for (int i = tid; i < 128 * 16; i += 512) acc[i] = 0.f;
    __syncthreads();

    const int eg = tid >> 4;  // 32 edge-groups
    const int c = tid & 15;
    for (int base = eg * 4; base < cnt; base += 128) {
        uint2 u[4];
        bool ok[4];
#pragma unroll
        for (int j = 0; j < 4; ++j) {
            ok[j] = (base + j) < cnt;
            u[j] = epk[start + (ok[j] ? base + j : base)];
        }
        unsigned g[4];
#pragma unroll
        for (int j = 0; j < 4; ++j)
            g[j] = hw01_u[(size_t)u[j].x * NCLS + c];
#pragma unroll
        for (int j = 0; j < 4; ++j) {
            if (ok[j]) {
                const int dl = u[j].y >> 24;
                const float v = (float)(u[j].y & 0xFFFFFFu) * 5.9604644775390625e-8f;
                const float m = (1.f - v) * bf2f((unsigned short)(g[j] & 0xFFFF)) +
                                v * bf2f((unsigned short)(g[j] >> 16));
                atomicAdd(&acc[dl * 16 + c], m);
            }
        }
    }
    __syncthreads();

    // softmax: 32 lane-groups handle dsts r = eg, eg+32, ...
    for (int r = eg; r < 128; r += 32) {
        const int n = (b << 7) + r;
        if (n < N_NODES) {
            const float z = acc[r * 16 + c] + agg2[(size_t)n * NCLS + c] + b2[c];
            float mx = z;
#pragma unroll
            for (int s = 1; s < 16; s <<= 1) mx = fmaxf(mx, __shfl_xor(mx, s, 64));
            const float e = expf(z - mx);
            float ssum = e;
#pragma unroll
            for (int s = 1; s < 16; s <<= 1) ssum += __shfl_xor(ssum, s, 64);
            out[(size_t)n * NCLS + c] = (z - mx) - logf(ssum);
        }
    }
}

extern "C" void kernel_launch(void* const* d_in, const int* in_sizes, int n_in,
                              void* d_out, int out_size, void* d_ws, size_t ws_size,
                              hipStream_t stream) {
    const float* x = (const float*)d_in[0];
    const int* ei = (const int*)d_in[1];
    const float* ea = (const float*)d_in[2];
    const float* w1 = (const float*)d_in[3];
    const float* root1 = (const float*)d_in[4];
    const float* b1 = (const float*)d_in[5];
    const float* w2 = (const float*)d_in[6];
    const float* root2 = (const float*)d_in[7];
    const float* b2 = (const float*)d_in[8];
    float* out = (float*)d_out;

    char* ws = (char*)d_ws;
    unsigned short* xw01 = (unsigned short*)ws;                 // 25.6 MB
    float* aggH = (float*)(ws + 25600000);                      // 25.6 MB
    unsigned* hw01_u = (unsigned*)(ws + 51200000);              // 6.4 MB
    float* agg2 = (float*)(ws + 57600000);                      // 6.4 MB
    unsigned short* Bt = (unsigned short*)(ws + 64000000);      // 0.2 MB
    int* bkcnt = (int*)(ws + 64300000);                         // 3.2 KB
    int* bkoff = (int*)(ws + 64310000);                         // 3.2 KB
    int* bkcur = (int*)(ws + 64320000);                         // 3.2 KB
    uint2* epk = (uint2*)(ws + 64400000);                       // 12.8 MB -> ~77.2 MB

    // bucket build (128-dst buckets; no per-dst sort)
    csr_bzero<<<1, 1024, 0, stream>>>(bkcnt);
    csr_bhist<<<(N_EDGES + EPB - 1) / EPB, 256, 0, stream>>>(ei, bkcnt);
    csr_bscan<<<1, 1024, 0, stream>>>(bkcnt, bkoff, bkcur);
    csr_bucket<<<(N_EDGES + EPB - 1) / EPB, 256, 0, stream>>>(ei, ea, bkcur, epk);

    // layer 1
    k0_bt<<<192, 256, 0, stream>>>(w1, root1, Bt);
    k1_mfma<<<(N_NODES + 63) / 64, 256, 0, stream>>>(x, Bt, xw01, aggH);
    agg1b<<<NBUK, 512, 0, stream>>>(bkoff, epk, (const unsigned*)xw01, aggH);

    // layer 2
    k3_relu_gemm<<<N_NODES / 16, 256, 0, stream>>>(aggH, b1, w2, root2, hw01_u, agg2);
    agg2b_sm<<<NBUK, 512, 0, stream>>>(bkoff, epk, hw01_u, agg2, b2, out);
}

// Round 10
// 301.554 us; speedup vs baseline: 3.4351x; 3.4351x over previous
//
#include <hip/hip_runtime.h>
#include <math.h>

#define N_NODES 100000
#define N_EDGES 1600000
#define IN_DIM 500
#define HID 64
#define NCLS 16
#define KP 512     // padded K for layer-1 GEMM
#define NSTEPS 16  // KP/32
#define NBUK 391     // buckets of 256 dsts: bucket = dst >> 8
#define NPAD (NBUK * 256)
#define EPB 4096     // edges per bucket-phase block

typedef __attribute__((ext_vector_type(8))) short short8;
typedef __attribute__((ext_vector_type(4))) float f32x4;

__device__ __forceinline__ unsigned short f2bf(float f) {
    unsigned u = __builtin_bit_cast(unsigned, f);
    return (unsigned short)((u + 0x7FFFu + ((u >> 16) & 1u)) >> 16);
}
__device__ __forceinline__ float bf2f(unsigned short s) {
    unsigned u = ((unsigned)s) << 16;
    return __builtin_bit_cast(float, u);
}
__device__ __forceinline__ unsigned pack2(unsigned short a, unsigned short b) {
    return (unsigned)a | ((unsigned)b << 16);
}
// async global->LDS, 16B per lane; LDS dest is wave-uniform base + lane*16
__device__ __forceinline__ void gload16(const void* g, void* l) {
    __builtin_amdgcn_global_load_lds(
        (const __attribute__((address_space(1))) unsigned*)g,
        (__attribute__((address_space(3))) unsigned*)l, 16, 0, 0);
}

// ---------------------------------------------------------------------------
// K0: build Bt[192][512] bf16 = transpose of {w1[0], w1[1], root1}, zero-pad K.
// ---------------------------------------------------------------------------
__global__ __launch_bounds__(256) void k0_bt(
    const float* __restrict__ w1, const float* __restrict__ root1,
    unsigned short* __restrict__ Bt)
{
    const int b = blockIdx.x;  // 0..191
    const float* src;
    int c;
    if (b < 64)        { src = w1;                c = b; }
    else if (b < 128)  { src = w1 + IN_DIM * HID; c = b - 64; }
    else               { src = root1;             c = b - 128; }
    for (int k = threadIdx.x; k < KP; k += 256) {
        float v = (k < IN_DIM) ? src[k * HID + c] : 0.f;
        Bt[b * KP + k] = f2bf(v);
    }
}

// ---------------------------------------------------------------------------
// CSR build, bucket-level:
//   bzero -> bhist (LDS hist of 391 buckets) -> bscan (1 block) ->
//   bucket (rank-scatter into bucket regions) -> place (per-dst offsets + final sort)
// ---------------------------------------------------------------------------
__global__ __launch_bounds__(512) void csr_bzero(int* __restrict__ bkcnt)
{
    if (threadIdx.x < NBUK) bkcnt[threadIdx.x] = 0;
}

__global__ __launch_bounds__(256) void csr_bhist(
    const int* __restrict__ ei, int* __restrict__ bkcnt)
{
    __shared__ int h[NBUK];
    const int tid = threadIdx.x;
    for (int i = tid; i < NBUK; i += 256) h[i] = 0;
    __syncthreads();
    const int start = blockIdx.x * EPB;
    const int eend = min(start + EPB, N_EDGES);
#pragma unroll
    for (int j = 0; j < EPB / 256; ++j) {
        const int e = start + j * 256 + tid;
        if (e < eend) atomicAdd(&h[ei[N_EDGES + e] >> 8], 1);
    }
    __syncthreads();
    for (int i = tid; i < NBUK; i += 256)
        if (h[i]) atomicAdd(&bkcnt[i], h[i]);
}

__global__ __launch_bounds__(512) void csr_bscan(
    const int* __restrict__ bkcnt, int* __restrict__ bkoff, int* __restrict__ bkcur)
{
    __shared__ int s[512];
    const int t = threadIdx.x;
    const int val = (t < NBUK) ? bkcnt[t] : 0;
    s[t] = val;
    for (int d = 1; d < 512; d <<= 1) {
        __syncthreads();
        int add = (t >= d) ? s[t - d] : 0;
        __syncthreads();
        s[t] += add;
    }
    __syncthreads();
    if (t < NBUK) {
        const int o = s[t] - val;
        bkoff[t] = o;
        bkcur[t] = o;
    }
    if (t == NBUK - 1) bkoff[NBUK] = s[t];  // == N_EDGES
}

// Phase 1: scatter edges into their 256-dst bucket region (arbitrary order
// within bucket). Record: x = src, y = (dstlow<<24) | v_fixed24.
__global__ __launch_bounds__(256) void csr_bucket(
    const int* __restrict__ ei, const float* __restrict__ ea,
    int* __restrict__ bkcur, uint2* __restrict__ epk)
{
    __shared__ int hcnt[NBUK];
    __shared__ int hbase[NBUK];

    const int tid = threadIdx.x;
    const int start = blockIdx.x * EPB;
    const int eend = min(start + EPB, N_EDGES);

    for (int i = tid; i < NBUK; i += 256) hcnt[i] = 0;
    __syncthreads();

#pragma unroll
    for (int j = 0; j < EPB / 256; ++j) {
        const int e = start + j * 256 + tid;
        if (e < eend) atomicAdd(&hcnt[ei[N_EDGES + e] >> 8], 1);
    }
    __syncthreads();

    for (int b = tid; b < NBUK; b += 256) {
        const int c = hcnt[b];
        hbase[b] = c ? atomicAdd(&bkcur[b], c) : 0;
    }
    __syncthreads();
    for (int i = tid; i < NBUK; i += 256) hcnt[i] = 0;
    __syncthreads();

#pragma unroll
    for (int j = 0; j < EPB / 256; ++j) {
        const int e = start + j * 256 + tid;
        if (e < eend) {
            const int src = ei[e];
            const int dst = ei[N_EDGES + e];
            const float v = fminf(fmaxf(ea[e], 0.f), 1.f - 1e-6f);
            const unsigned vq = (unsigned)(v * 16777216.0f);  // 24-bit fixed
            const int bk = dst >> 8;
            const int r = atomicAdd(&hcnt[bk], 1);
            epk[hbase[bk] + r] =
                make_uint2((unsigned)src, ((unsigned)(dst & 255) << 24) | vq);
        }
    }
}

// Phase 2: per bucket, 2-pass: (a) LDS hist of 256 dsts + LDS scan -> global
// off[]; (b) re-read records, rank via LDS atomics, write (src, v_f32) to epkS.
__global__ __launch_bounds__(256) void csr_place(
    const int* __restrict__ bkoff, const uint2* __restrict__ epk,
    uint2* __restrict__ epkS, int* __restrict__ off)
{
    __shared__ int hist[256];
    __shared__ int sc[256];
    __shared__ int cur[256];

    const int b = blockIdx.x;
    const int tid = threadIdx.x;
    const int start = bkoff[b];
    const int end = bkoff[b + 1];
    const int cnt = end - start;

    hist[tid] = 0;
    __syncthreads();
    for (int i = tid; i < cnt; i += 256)
        atomicAdd(&hist[epk[start + i].y >> 24], 1);
    __syncthreads();

    const int val = hist[tid];
    sc[tid] = val;
    for (int d = 1; d < 256; d <<= 1) {
        __syncthreads();
        int add = (tid >= d) ? sc[tid - d] : 0;
        __syncthreads();
        sc[tid] += add;
    }
    __syncthreads();
    const int mystart = start + sc[tid] - val;  // exclusive
    off[(b << 8) + tid] = mystart;
    cur[tid] = mystart;
    __syncthreads();

    for (int i = tid; i < cnt; i += 256) {
        const uint2 u = epk[start + i];
        const int dl = u.y >> 24;
        const float v = (float)(u.y & 0xFFFFFFu) * 5.9604644775390625e-8f;
        const int pos = atomicAdd(&cur[dl], 1);
        epkS[pos] = make_uint2(u.x, __builtin_bit_cast(unsigned, v));
    }
}

// ---------------------------------------------------------------------------
// K1: bf16 MFMA GEMM. global_load_lds staging (A fp32, B bf16), FOUR LDS
// buffers, depth-2 prefetch, counted vmcnt + raw s_barrier (T3/T4 minimum).
// Tile: 64 rows x 192 cols, BK=32. 4 waves in 2x2.
// ---------------------------------------------------------------------------
union K1Smem {
    struct { float A[4][64 * 32]; unsigned short B[4][192 * 32]; } s;  // 80KB
    unsigned short O[64 * 264];  // epilogue staging (33.8 KB)
};

__global__ __launch_bounds__(256) void k1_mfma(
    const float* __restrict__ x, const unsigned short* __restrict__ Bt,
    unsigned short* __restrict__ xw01, float* __restrict__ aggH)
{
    __shared__ K1Smem sm;

    const int tid = threadIdx.x;
    const int row0 = blockIdx.x * 64;
    const int w = tid >> 6;
    const int l = tid & 63;
    const int l16 = l & 15;
    const int koct = l >> 4;
    const int wr = w >> 1;
    const int wc = w & 1;

    f32x4 acc[2][6];
#pragma unroll
    for (int i = 0; i < 2; ++i)
#pragma unroll
        for (int j = 0; j < 6; ++j) acc[i][j] = (f32x4){0.f, 0.f, 0.f, 0.f};

    const int aJg4 = (((l & 7) ^ (l >> 3)) * 4);
    const float* aBase[2];
    int aLdsOff[2];
#pragma unroll
    for (int i = 0; i < 2; ++i) {
        const int rowl = (2 * w + i) * 8 + (l >> 3);
        int grow = row0 + rowl;
        if (grow > N_NODES - 1) grow = N_NODES - 1;
        aBase[i] = x + (size_t)grow * IN_DIM;
        aLdsOff[i] = (2 * w + i) * 256;  // floats
    }
    const int bJg8 = (((l & 3) ^ ((l >> 3) & 3)) * 8);
    const unsigned short* bBase[3];
    int bLdsOff[3];
#pragma unroll
    for (int i = 0; i < 3; ++i) {
        const int coll = (3 * w + i) * 16 + (l >> 2);
        bBase[i] = Bt + (size_t)coll * KP + bJg8;
        bLdsOff[i] = (3 * w + i) * 512;  // ushorts
    }

    const int ja0 = ((2 * koct) ^ (l16 & 7)) * 4;
    const int ja1 = ((2 * koct + 1) ^ (l16 & 7)) * 4;
    const int jb = (koct ^ ((l16 >> 1) & 3)) * 8;

    auto ISSUE = [&](int s) {
        const int k0 = s * 32;
        const int buf = s & 3;
#pragma unroll
        for (int i = 0; i < 2; ++i) {
            int gk = k0 + aJg4; if (gk > IN_DIM - 4) gk = IN_DIM - 4;
            gload16(aBase[i] + gk, &sm.s.A[buf][aLdsOff[i]]);
        }
#pragma unroll
        for (int i = 0; i < 3; ++i)
            gload16(bBase[i] + k0, &sm.s.B[buf][bLdsOff[i]]);
    };

    ISSUE(0);
    ISSUE(1);

#pragma unroll
    for (int s = 0; s < NSTEPS; ++s) {
        if (s + 2 < NSTEPS) ISSUE(s + 2);
        if (s < NSTEPS - 2)       asm volatile("s_waitcnt vmcnt(10)" ::: "memory");
        else if (s == NSTEPS - 2) asm volatile("s_waitcnt vmcnt(5)" ::: "memory");
        else                      asm volatile("s_waitcnt vmcnt(0)" ::: "memory");
        __builtin_amdgcn_s_barrier();
        asm volatile("" ::: "memory");

        const int buf = s & 3;
        const float* LA = sm.s.A[buf];
        const unsigned short* LB = sm.s.B[buf];
        short8 af[2];
#pragma unroll
        for (int rb = 0; rb < 2; ++rb) {
            const int r = wr * 32 + rb * 16 + l16;
            f32x4 f0 = *(const f32x4*)&LA[r * 32 + ja0];
            f32x4 f1 = *(const f32x4*)&LA[r * 32 + ja1];
            short8 a;
            a[0] = (short)f2bf(f0[0]); a[1] = (short)f2bf(f0[1]);
            a[2] = (short)f2bf(f0[2]); a[3] = (short)f2bf(f0[3]);
            a[4] = (short)f2bf(f1[0]); a[5] = (short)f2bf(f1[1]);
            a[6] = (short)f2bf(f1[2]); a[7] = (short)f2bf(f1[3]);
            af[rb] = a;
        }
#pragma unroll
        for (int cf = 0; cf < 6; ++cf) {
            const int c = wc * 96 + cf * 16 + l16;
            short8 bfg = *(const short8*)&LB[c * 32 + jb];
            acc[0][cf] = __builtin_amdgcn_mfma_f32_16x16x32_bf16(af[0], bfg, acc[0][cf], 0, 0, 0);
            acc[1][cf] = __builtin_amdgcn_mfma_f32_16x16x32_bf16(af[1], bfg, acc[1][cf], 0, 0, 0);
        }
    }
    __syncthreads();

#pragma unroll
    for (int rb = 0; rb < 2; ++rb)
#pragma unroll
        for (int cf = 0; cf < 6; ++cf) {
            const int cg = wc * 96 + cf * 16 + l16;
            if (96 * wc + cf * 16 < 128) {
#pragma unroll
                for (int reg = 0; reg < 4; ++reg) {
                    const int rloc = wr * 32 + rb * 16 + koct * 4 + reg;
                    const int idx = (cg < 64) ? (2 * cg) : (2 * cg - 127);
                    sm.O[rloc * 264 + idx] = f2bf(acc[rb][cf][reg]);
                }
            } else {
#pragma unroll
                for (int reg = 0; reg < 4; ++reg) {
                    const int r = row0 + wr * 32 + rb * 16 + koct * 4 + reg;
                    if (r < N_NODES) aggH[(size_t)r * HID + (cg - 128)] = acc[rb][cf][reg];
                }
            }
        }
    __syncthreads();
    {
        const int row = tid >> 2, q = tid & 3;
        const int rg = row0 + row;
        if (rg < N_NODES) {
#pragma unroll
            for (int j = 0; j < 4; ++j) {
                uint4 v = *(const uint4*)&sm.O[row * 264 + q * 32 + j * 8];
                *(uint4*)&xw01[(size_t)rg * 128 + q * 32 + j * 8] = v;
            }
        }
    }
}

// ---------------------------------------------------------------------------
// AGG1: wave per node; lane = hidden dim. acc = aggH(root) + sum over edges.
// 8 edges in flight (two latency rounds for mean degree 16).
// ---------------------------------------------------------------------------
__global__ __launch_bounds__(256) void agg1(
    const int* __restrict__ off, const uint2* __restrict__ epk,
    const unsigned* __restrict__ xw01_u, float* __restrict__ aggH)
{
    const int n = blockIdx.x * 4 + (threadIdx.x >> 6);
    if (n >= N_NODES) return;
    const int d = threadIdx.x & 63;
    const int start = off[n];
    const int deg = off[n + 1] - start;

    float acc = aggH[(size_t)n * HID + d];
    for (int i = 0; i < deg; i += 8) {
        unsigned srcs[8];
        float w0[8], w1[8];
#pragma unroll
        for (int j = 0; j < 8; ++j) {
            const bool ok = (i + j) < deg;
            const int idx = ok ? (start + i + j) : start;
            const uint2 t = epk[idx];
            const float v = __builtin_bit_cast(float, t.y);
            srcs[j] = t.x;
            w0[j] = ok ? (1.f - v) : 0.f;
            w1[j] = ok ? v : 0.f;
        }
        unsigned g[8];
#pragma unroll
        for (int j = 0; j < 8; ++j) g[j] = xw01_u[(size_t)srcs[j] * 64 + d];
#pragma unroll
        for (int j = 0; j < 8; ++j) {
            acc += w0[j] * bf2f((unsigned short)(g[j] & 0xFFFF));
            acc += w1[j] * bf2f((unsigned short)(g[j] >> 16));
        }
    }
    aggH[(size_t)n * HID + d] = acc;
}

// ---------------------------------------------------------------------------
// K3: h = relu(aggH + b1); hw01 = packed bf16 {h@w2[0], h@w2[1]}; agg2 = h@root2.
// ---------------------------------------------------------------------------
__global__ __launch_bounds__(256) void k3_relu_gemm(
    const float* __restrict__ aggH, const float* __restrict__ b1,
    const float* __restrict__ w2, const float* __restrict__ root2,
    unsigned* __restrict__ hw01_u, float* __restrict__ agg2)
{
    __shared__ float Ws[3 * HID * NCLS];
    __shared__ float Hs[16][HID];

    const int tid = threadIdx.x;
    for (int i = tid; i < 2 * HID * NCLS; i += 256) Ws[i] = w2[i];
    for (int i = tid; i < HID * NCLS; i += 256) Ws[2 * HID * NCLS + i] = root2[i];

    const int n0 = blockIdx.x * 16;
    for (int i = tid; i < 16 * HID; i += 256) {
        const int nl = i >> 6, k = i & 63;
        const float h = aggH[(size_t)(n0 + nl) * HID + k] + b1[k];
        Hs[nl][k] = fmaxf(h, 0.f);
    }
    __syncthreads();

    const int nl = tid >> 4;
    const int c = tid & 15;
    float a0 = 0.f, a1 = 0.f, a2 = 0.f;
#pragma unroll
    for (int k = 0; k < HID; ++k) {
        const float h = Hs[nl][k];
        a0 += h * Ws[0 * HID * NCLS + k * NCLS + c];
        a1 += h * Ws[1 * HID * NCLS + k * NCLS + c];
        a2 += h * Ws[2 * HID * NCLS + k * NCLS + c];
    }
    const size_t o = (size_t)(n0 + nl) * NCLS + c;
    hw01_u[o] = pack2(f2bf(a0), f2bf(a1));
    agg2[o] = a2;
}

// ---------------------------------------------------------------------------
// AGG2 + log_softmax fused: 16 lanes per node, 16 nodes per block.
// 8 edges in flight.
// ---------------------------------------------------------------------------
__global__ __launch_bounds__(256) void agg2_sm(
    const int* __restrict__ off, const uint2* __restrict__ epk,
    const unsigned* __restrict__ hw01_u, const float* __restrict__ agg2,
    const float* __restrict__ b2, float* __restrict__ out)
{
    const int n = blockIdx.x * 16 + (threadIdx.x >> 4);
    const int c = threadIdx.x & 15;
    const int start = off[n];
    const int deg = off[n + 1] - start;

    float acc = agg2[(size_t)n * NCLS + c];
    for (int i = 0; i < deg; i += 8) {
        unsigned srcs[8];
        float w0[8], w1[8];
#pragma unroll
        for (int j = 0; j < 8; ++j) {
            const bool ok = (i + j) < deg;
            const int idx = ok ? (start + i + j) : start;
            const uint2 t = epk[idx];
            const float v = __builtin_bit_cast(float, t.y);
            srcs[j] = t.x;
            w0[j] = ok ? (1.f - v) : 0.f;
            w1[j] = ok ? v : 0.f;
        }
        unsigned g[8];
#pragma unroll
        for (int j = 0; j < 8; ++j) g[j] = hw01_u[(size_t)srcs[j] * NCLS + c];
#pragma unroll
        for (int j = 0; j < 8; ++j) {
            acc += w0[j] * bf2f((unsigned short)(g[j] & 0xFFFF));
            acc += w1[j] * bf2f((unsigned short)(g[j] >> 16));
        }
    }

    const float z = acc + b2[c];
    float m = z;
#pragma unroll
    for (int s = 1; s < 16; s <<= 1) m = fmaxf(m, __shfl_xor(m, s, 64));
    const float e = expf(z - m);
    float ssum = e;
#pragma unroll
    for (int s = 1; s < 16; s <<= 1) ssum += __shfl_xor(ssum, s, 64);
    out[(size_t)n * NCLS + c] = (z - m) - logf(ssum);
}

extern "C" void kernel_launch(void* const* d_in, const int* in_sizes, int n_in,
                              void* d_out, int out_size, void* d_ws, size_t ws_size,
                              hipStream_t stream) {
    const float* x = (const float*)d_in[0];
    const int* ei = (const int*)d_in[1];
    const float* ea = (const float*)d_in[2];
    const float* w1 = (const float*)d_in[3];
    const float* root1 = (const float*)d_in[4];
    const float* b1 = (const float*)d_in[5];
    const float* w2 = (const float*)d_in[6];
    const float* root2 = (const float*)d_in[7];
    const float* b2 = (const float*)d_in[8];
    float* out = (float*)d_out;

    char* ws = (char*)d_ws;
    unsigned short* xw01 = (unsigned short*)ws;                 // 25.6 MB
    float* aggH = (float*)(ws + 25600000);                      // 25.6 MB
    unsigned* hw01_u = (unsigned*)(ws + 51200000);              // 6.4 MB
    float* agg2 = (float*)(ws + 57600000);                      // 6.4 MB
    unsigned short* Bt = (unsigned short*)(ws + 64000000);      // 0.2 MB
    int* off = (int*)(ws + 64300000);                           // 0.4 MB (NPAD ints)
    int* bkcnt = (int*)(ws + 64750000);                         // 1.6 KB
    int* bkoff = (int*)(ws + 64760000);                         // 1.6 KB
    int* bkcur = (int*)(ws + 64770000);                         // 1.6 KB
    uint2* epk = (uint2*)(ws + 64800000);                       // 12.8 MB
    uint2* epkS = (uint2*)(ws + 77600000);                      // 12.8 MB -> ~90.4 MB

    // CSR build (bucket-level histogram; per-dst offsets from csr_place)
    csr_bzero<<<1, 512, 0, stream>>>(bkcnt);
    csr_bhist<<<(N_EDGES + EPB - 1) / EPB, 256, 0, stream>>>(ei, bkcnt);
    csr_bscan<<<1, 512, 0, stream>>>(bkcnt, bkoff, bkcur);
    csr_bucket<<<(N_EDGES + EPB - 1) / EPB, 256, 0, stream>>>(ei, ea, bkcur, epk);
    csr_place<<<NBUK, 256, 0, stream>>>(bkoff, epk, epkS, off);

    // layer 1
    k0_bt<<<192, 256, 0, stream>>>(w1, root1, Bt);
    k1_mfma<<<(N_NODES + 63) / 64, 256, 0, stream>>>(x, Bt, xw01, aggH);
    agg1<<<(N_NODES + 3) / 4, 256, 0, stream>>>(off, epkS, (const unsigned*)xw01, aggH);

    // layer 2
    k3_relu_gemm<<<N_NODES / 16, 256, 0, stream>>>(aggH, b1, w2, root2, hw01_u, agg2);
    agg2_sm<<<N_NODES / 16, 256, 0, stream>>>(off, epkS, hw01_u, agg2, b2, out);
}